// Round 12
// baseline (124.714 us; speedup 1.0000x reference)
//
#include <hip/hip_runtime.h>
#include <math.h>

// B=32, S=32, LQ=30, LS=40, D=300, F=256, FS=3, K=5
// out layout: [0]=total_loss, [1..1024]=sent_output(B,S), [1025..1056]=doc_em(B)

typedef __attribute__((ext_vector_type(4))) float f32x4;
typedef __attribute__((ext_vector_type(8))) short s16x8;

__device__ inline ushort bf16rne(float f) {
  unsigned u = __float_as_uint(f);
  u += 0x7fff + ((u >> 16) & 1);
  return (ushort)(u >> 16);
}
__device__ inline uint pack2(float a, float b) {
  return (uint)bf16rne(a) | ((uint)bf16rne(b) << 16);
}
__device__ inline float ubf(short h) { return __uint_as_float(((uint)(ushort)h) << 16); }

// Fused prep: blocks [0,120) pack filters into fB (4 old-bids per block);
// blocks [120,1176) gather+pack one sequence's embeds rows into xsg
// (bf16, pre-swizzled: flat ^ (row&7)<<3), zero-padded. Slot = 16000 ush/seq.
__global__ __launch_bounds__(256) void k_prep_gather(const float* __restrict__ filters,
                                                     ushort* __restrict__ fB,
                                                     const int* __restrict__ question,
                                                     const int* __restrict__ sentences,
                                                     const float* __restrict__ embeds,
                                                     ushort* __restrict__ xsg) {
  __shared__ int tok[64];
  const int blk = blockIdx.x;
  const int tid = threadIdx.x;
  if (blk < 120) {
    // ---- filter pack (old k_prepB, bid = blk*4 + wave) ----
    const int bid = blk * 4 + (tid >> 6);        // 0..479
    const int lane = tid & 63;
    const int nt = bid & 15;
    const int tk = bid >> 4;
    const int tap = tk / 10, kstep = tk - tap * 10;
    const int f = nt * 16 + (lane & 15);
    const int kb = kstep * 32 + (lane >> 4) * 8;
    uint p[4];
#pragma unroll
    for (int h = 0; h < 4; ++h) {
      int d0 = kb + h * 2, d1 = kb + h * 2 + 1;
      float v0 = (d0 < 300) ? filters[(size_t)f * 900 + tap * 300 + d0] : 0.f;
      float v1 = (d1 < 300) ? filters[(size_t)f * 900 + tap * 300 + d1] : 0.f;
      p[h] = (uint)bf16rne(v0) | ((uint)bf16rne(v1) << 16);
    }
    *(uint4*)(fB + ((size_t)bid * 64 + lane) * 8) = make_uint4(p[0], p[1], p[2], p[3]);
  } else {
    const int g = blk - 120;                     // 0..1055 (slot index)
    const int L = (g < 1024) ? 40 : 30;
    const int ROWS = (g < 1024) ? 50 : 34;
    const int* tokens = (g < 1024) ? (sentences + (size_t)g * 40)
                                   : (question + (size_t)(g - 1024) * 30);
    if (tid < L) tok[tid] = tokens[tid];
    __syncthreads();
    ushort* dst = xsg + (size_t)g * 16000;
    const int items = ROWS * 80;                 // float4 slots
    for (int idx = tid; idx < items; idx += 256) {
      int row = idx / 80;
      int d = (idx - row * 80) * 4;
      float4 v = make_float4(0.f, 0.f, 0.f, 0.f);
      if (row < L && d < 300) v = *(const float4*)(embeds + (size_t)tok[row] * 300 + d);
      int flat = row * 320 + d;
      *(uint2*)(dst + (flat ^ ((row & 7) << 3))) =
          make_uint2(pack2(v.x, v.y), pack2(v.z, v.w));
    }
  }
}

// Conv body: stage xsg slot -> LDS (coalesced copy, already swizzled), norms,
// conv MFMA, writeback, blobC pack (+ blobA pack only for the question path).
template<int L, int MT, int ROWS_ST, bool EMIT_A>
__device__ __forceinline__ void conv_body(int slot, int seq,
                                          const ushort* __restrict__ xsg,
                                          const ushort* __restrict__ fB,
                                          ushort* __restrict__ blobA,
                                          ushort* __restrict__ blobC,
                                          float* __restrict__ rcpA,
                                          float* __restrict__ rcpC,
                                          ushort* xs) {
  const int tid = threadIdx.x;

  // ---- stage: coalesced copy of the pre-swizzled slot ----
  {
    const uint4* src = (const uint4*)(xsg + (size_t)slot * 16000);
    uint4* dst = (uint4*)xs;
    constexpr int NV = ROWS_ST * 40;             // uint4 per slot region
    for (int i = tid; i < NV; i += 256) dst[i] = src[i];
  }
  __syncthreads();

  const int wv = tid >> 6, lane = tid & 63;
  const int lr = lane & 15, lh = lane >> 4;

  if (EMIT_A) {
    for (int t = wv; t < 10 * MT; t += 4) {
      int kstep = t / MT, tile = t - kstep * MT;
      int row = tile * 16 + lr;
      int flat = row * 320 + kstep * 32 + lh * 8;
      s16x8 v = *(const s16x8*)(xs + (flat ^ ((row & 7) << 3)));
      *(s16x8*)(blobA + ((((size_t)seq * 10 + kstep) * MT + tile) * 64 + lane) * 8) = v;
    }
  }
  // ---- phase-0 norms ----
  if (tid < L) {
    int row = tid;
    float s = 0.f;
    for (int c = 0; c < 40; ++c) {
      int flat = row * 320 + c * 8;
      s16x8 v = *(const s16x8*)(xs + (flat ^ ((row & 7) << 3)));
#pragma unroll
      for (int i = 0; i < 8; ++i) { float f = ubf(v[i]); s += f * f; }
    }
    rcpA[(size_t)seq * L + row] = (s > 0.f) ? rsqrtf(s) : 0.f;
  }

  // ---- conv MFMA ----
  f32x4 acc[MT][4];
#pragma unroll
  for (int mt = 0; mt < MT; ++mt)
#pragma unroll
    for (int n = 0; n < 4; ++n)
#pragma unroll
      for (int r = 0; r < 4; ++r) acc[mt][n][r] = 0.f;

  const s16x8* fBv = (const s16x8*)fB;
  for (int kstep = 0; kstep < 10; ++kstep) {
#pragma unroll
    for (int tap = 0; tap < 3; ++tap) {
      s16x8 b[4];
#pragma unroll
      for (int n = 0; n < 4; ++n)
        b[n] = fBv[((size_t)((tap * 10 + kstep) * 16 + (wv * 4 + n))) * 64 + lane];
#pragma unroll
      for (int mt = 0; mt < MT; ++mt) {
        int row = mt * 16 + lr + tap;
        int flat = row * 320 + kstep * 32 + lh * 8;
        s16x8 a = *(const s16x8*)(xs + (flat ^ ((row & 7) << 3)));
#pragma unroll
        for (int n = 0; n < 4; ++n)
          acc[mt][n] = __builtin_amdgcn_mfma_f32_16x16x32_bf16(a, b[n], acc[mt][n], 0, 0, 0);
      }
    }
  }
  __syncthreads();   // all xs readers (norms, MFMA A-frags, blobA) done

  // ---- write conv output back into xs as bf16 (rows j<L, cols<256) ----
#pragma unroll
  for (int mt = 0; mt < MT; ++mt)
#pragma unroll
    for (int n = 0; n < 4; ++n)
#pragma unroll
      for (int r = 0; r < 4; ++r) {
        int j = mt * 16 + lh * 4 + r;
        if (j < L) {
          int f = wv * 64 + n * 16 + lr;
          int flat = j * 320 + f;
          xs[flat ^ ((j & 7) << 3)] = bf16rne(acc[mt][n][r]);
        }
      }
  __syncthreads();

  // ---- pack blobC (phase-1 sim fragments, KS=8) ----
  for (int t = wv; t < 8 * MT; t += 4) {
    int kstep = t / MT, tile = t - kstep * MT;
    int row = tile * 16 + lr;
    int flat = row * 320 + kstep * 32 + lh * 8;
    s16x8 v = *(const s16x8*)(xs + (flat ^ ((row & 7) << 3)));
    *(s16x8*)(blobC + ((((size_t)seq * 8 + kstep) * MT + tile) * 64 + lane) * 8) = v;
  }
  // ---- phase-1 norms (cols 0..255) ----
  if (tid < L) {
    int row = tid;
    float s = 0.f;
    for (int c = 0; c < 32; ++c) {
      int flat = row * 320 + c * 8;
      s16x8 v = *(const s16x8*)(xs + (flat ^ ((row & 7) << 3)));
#pragma unroll
      for (int i = 0; i < 8; ++i) { float f = ubf(v[i]); s += f * f; }
    }
    rcpC[(size_t)seq * L + row] = (s > 0.f) ? rsqrtf(s) : 0.f;
  }
}

// Merged conv dispatch: [0,1024) sentence (L=40, no blobA), [1024,1056) question.
__global__ __launch_bounds__(256) void k_conv_all(const ushort* __restrict__ xsg,
                                                  const ushort* __restrict__ fB,
                                                  ushort* __restrict__ scb,
                                                  ushort* __restrict__ qeb,
                                                  ushort* __restrict__ qcb,
                                                  float* __restrict__ rs0,
                                                  float* __restrict__ rs1,
                                                  float* __restrict__ rq0,
                                                  float* __restrict__ rq1) {
  __shared__ __align__(16) ushort xs[50 * 320];   // 32 KB (max path)
  const int bid = blockIdx.x;
  if (bid < 1024) {
    conv_body<40, 3, 50, false>(bid, bid, xsg, fB, nullptr, scb, rs0, rs1, xs);
  } else {
    conv_body<30, 2, 34, true>(bid, bid - 1024, xsg, fB, qeb, qcb, rq0, rq1, xs);
  }
}

// One block per (b,s): phase-0 B-frags from LDS-staged xsg rows (swizzled, proven
// pattern); phase-1 from scb blob; A-frags from qeb/qcb; then top-5 pooling.
__global__ __launch_bounds__(256) void k_sim(const float* __restrict__ oneh,
                                             const ushort* __restrict__ xsg,
                                             const ushort* __restrict__ qeb,
                                             const ushort* __restrict__ qcb,
                                             const ushort* __restrict__ scb,
                                             const float* __restrict__ rq0,
                                             const float* __restrict__ rs0,
                                             const float* __restrict__ rq1,
                                             const float* __restrict__ rs1,
                                             const float* __restrict__ lin_w,
                                             const float* __restrict__ lin_b,
                                             float* __restrict__ out) {
  const int bs = blockIdx.x;
  const int b = bs >> 5;
  const int tid = threadIdx.x;
  const int wv = tid >> 6, lane = tid & 63;
  const int lr = lane & 15, lh = lane >> 4;

  __shared__ __align__(16) ushort xs2[48 * 320];   // 30 KB: se rows 0..47 (swizzled)
  __shared__ float simb[2][30][49];
  __shared__ float ohl[30 * 41];
  __shared__ float rQ[2][30], rS[2][40];
  __shared__ float feats[30][6];
  __shared__ float lo[30];

  if (tid < 30) rQ[0][tid] = rq0[b * 30 + tid];
  else if (tid < 60) rQ[1][tid - 30] = rq1[b * 30 + (tid - 30)];
  else if (tid < 100) rS[0][tid - 60] = rs0[(size_t)bs * 40 + (tid - 60)];
  else if (tid < 140) rS[1][tid - 100] = rs1[(size_t)bs * 40 + (tid - 100)];
  {
    const float* og = oneh + (size_t)bs * 1200;
    for (int i = tid; i < 1200; i += 256) {
      int q = i / 40, l = i - q * 40;
      ohl[q * 41 + l] = og[i];
    }
  }
  {
    const uint4* src = (const uint4*)(xsg + (size_t)bs * 16000);
    uint4* dst = (uint4*)xs2;
    for (int i = tid; i < 1920; i += 256) dst[i] = src[i];   // 48*320 ush
  }
  __syncthreads();

  // 6 wave-tasks: (ph, nt)
  for (int task = wv; task < 6; task += 4) {
    int ph = task / 3, nt = task - ph * 3;
    int KS = ph ? 8 : 10;
    const ushort* Ab = ph ? (qcb + (size_t)b * 8 * 2 * 512) : (qeb + (size_t)b * 10 * 2 * 512);
    const ushort* Bb = scb + (size_t)bs * 8 * 3 * 512;       // ph==1 only
    f32x4 acc0 = {0.f, 0.f, 0.f, 0.f};
    f32x4 acc1 = {0.f, 0.f, 0.f, 0.f};
    int brow = nt * 16 + lr;
    for (int k = 0; k < KS; ++k) {
      s16x8 bf;
      if (ph == 0) {
        int flat = brow * 320 + k * 32 + lh * 8;
        bf = *(const s16x8*)(xs2 + (flat ^ ((brow & 7) << 3)));
      } else {
        bf = *(const s16x8*)(Bb + ((size_t)(k * 3 + nt) * 64 + lane) * 8);
      }
      s16x8 a0 = *(const s16x8*)(Ab + ((size_t)(k * 2 + 0) * 64 + lane) * 8);
      s16x8 a1 = *(const s16x8*)(Ab + ((size_t)(k * 2 + 1) * 64 + lane) * 8);
      acc0 = __builtin_amdgcn_mfma_f32_16x16x32_bf16(a0, bf, acc0, 0, 0, 0);
      acc1 = __builtin_amdgcn_mfma_f32_16x16x32_bf16(a1, bf, acc1, 0, 0, 0);
    }
    int l = nt * 16 + lr;
    if (l < 40) {
#pragma unroll
      for (int r = 0; r < 4; ++r) {
        int q0 = lh * 4 + r;                       // < 16
        simb[ph][q0][l] = acc0[r] * rQ[ph][q0] * rS[ph][l];
        int q1 = 16 + lh * 4 + r;
        if (q1 < 30) simb[ph][q1][l] = acc1[r] * rQ[ph][q1] * rS[ph][l];
      }
    }
  }
  __syncthreads();

  // duplicate-safe top-5 pooling on 90 threads
  if (tid < 90) {
    const int m = tid / 30, q = tid - m * 30;
    const float* row = (m == 0) ? &simb[0][q][0] : (m == 1) ? &simb[1][q][0] : (ohl + q * 41);
    float thr = 3.4e38f;
    int got = 0;
    float sum = 0.f, maxv = 0.f;
    while (got < 5) {
      float mx = -3.4e38f;
      int c = 0;
      for (int l = 0; l < 40; ++l) {
        float v = row[l];
        if (v < thr) {
          if (v > mx) { mx = v; c = 1; }
          else if (v == mx) { c++; }
        }
      }
      if (c == 0) break;  // safety: never hang
      if (got == 0) maxv = mx;
      int take = (c < 5 - got) ? c : (5 - got);
      sum += mx * (float)take;
      got += take;
      thr = mx;
    }
    feats[q][m * 2 + 0] = maxv;
    feats[q][m * 2 + 1] = sum * 0.2f;
  }
  __syncthreads();
  if (tid < 30) {
    float z = lin_b[0];
#pragma unroll
    for (int i = 0; i < 6; ++i) z += feats[tid][i] * lin_w[i];
    lo[tid] = 1.0f / (1.0f + expf(-z));
  }
  __syncthreads();
  if (tid == 0) {
    float sum = 0.f;
    for (int q = 0; q < 30; ++q) sum += lo[q];
    out[1 + bs] = sum * (1.0f / 30.0f);
  }
}

__global__ __launch_bounds__(256) void k_loss(const int* __restrict__ tsent,
                                              const int* __restrict__ tdoc,
                                              float* __restrict__ out) {
  __shared__ float red[256];
  __shared__ float sent_loss_sh;
  const int tid = threadIdx.x;
  float local = 0.f;
  for (int i = tid; i < 1024; i += 256) {
    float p = out[1 + i];
    float t = (float)tsent[i];
    float lp = fmaxf(logf(p), -100.f);
    float l1 = fmaxf(logf(1.f - p), -100.f);
    local += -(t * lp + (1.f - t) * l1);
  }
  red[tid] = local;
  __syncthreads();
  for (int off = 128; off > 0; off >>= 1) {
    if (tid < off) red[tid] += red[tid + off];
    __syncthreads();
  }
  if (tid == 0) sent_loss_sh = red[0] * (1.0f / 1024.0f);
  __syncthreads();
  float dterm = 0.f;
  if (tid < 32) {
    float mx = out[1 + tid * 32];
    for (int s2 = 1; s2 < 32; ++s2) mx = fmaxf(mx, out[1 + tid * 32 + s2]);
    out[1025 + tid] = mx;
    float t = (float)tdoc[tid];
    float lp = fmaxf(logf(mx), -100.f);
    float l1 = fmaxf(logf(1.f - mx), -100.f);
    dterm = -(t * lp + (1.f - t) * l1);
  }
  red[tid] = dterm;
  __syncthreads();
  for (int off = 128; off > 0; off >>= 1) {
    if (tid < off) red[tid] += red[tid + off];
    __syncthreads();
  }
  if (tid == 0) out[0] = 0.5f * (sent_loss_sh + red[0] * (1.0f / 32.0f));
}

extern "C" void kernel_launch(void* const* d_in, const int* in_sizes, int n_in,
                              void* d_out, int out_size, void* d_ws, size_t ws_size,
                              hipStream_t stream) {
  const int*   question     = (const int*)d_in[0];
  const int*   sentences    = (const int*)d_in[1];
  const int*   target_sents = (const int*)d_in[2];
  const int*   target_docs  = (const int*)d_in[3];
  const float* oneh         = (const float*)d_in[4];
  const float* embeds       = (const float*)d_in[5];
  const float* filters      = (const float*)d_in[6];
  const float* lin_w        = (const float*)d_in[7];
  const float* lin_b        = (const float*)d_in[8];
  float* out = (float*)d_out;

  // workspace layout:
  ushort* fB  = (ushort*)d_ws;             // 245,760 ush
  ushort* xsg = fB  + 245760;              // 1056*16000 = 16,896,000 ush (33.8 MB)
  ushort* scb = xsg + 16896000;            // 1024*8*3*512 = 12,582,912 ush (24 MB)
  ushort* qeb = scb + 12582912;            // 32*10*2*512  = 327,680 ush
  ushort* qcb = qeb + 327680;              // 32*8*2*512   = 262,144 ush
  float*  rs0 = (float*)(qcb + 262144);    // 1024*40
  float*  rs1 = rs0 + 40960;               // 1024*40
  float*  rq0 = rs1 + 40960;               // 32*30
  float*  rq1 = rq0 + 960;                 // 32*30

  k_prep_gather<<<1176, 256, 0, stream>>>(filters, fB, question, sentences, embeds, xsg);
  k_conv_all<<<1056, 256, 0, stream>>>(xsg, fB, scb, qeb, qcb, rs0, rs1, rq0, rq1);
  k_sim<<<1024, 256, 0, stream>>>(oneh, xsg, qeb, qcb, scb, rq0, rs0, rq1, rs1,
                                  lin_w, lin_b, out);
  k_loss<<<1, 256, 0, stream>>>(target_sents, target_docs, out);
}

// Round 13
// 114.468 us; speedup vs baseline: 1.0895x; 1.0895x over previous
//
#include <hip/hip_runtime.h>
#include <math.h>

// B=32, S=32, LQ=30, LS=40, D=300, F=256, FS=3, K=5
// out layout: [0]=total_loss, [1..1024]=sent_output(B,S), [1025..1056]=doc_em(B)

typedef __attribute__((ext_vector_type(4))) float f32x4;
typedef __attribute__((ext_vector_type(8))) short s16x8;

__device__ inline ushort bf16rne(float f) {
  unsigned u = __float_as_uint(f);
  u += 0x7fff + ((u >> 16) & 1);
  return (ushort)(u >> 16);
}
__device__ inline uint pack2(float a, float b) {
  return (uint)bf16rne(a) | ((uint)bf16rne(b) << 16);
}
__device__ inline float ubf(short h) { return __uint_as_float(((uint)(ushort)h) << 16); }

// Pack filters into MFMA B-fragment-major layout:
// fB[((tap*10+kstep)*16 + nt)*64 + lane][8] ; B[k][col]: col=lane&15, k=(lane>>4)*8+i
__global__ __launch_bounds__(64) void k_prepB(const float* __restrict__ filters,
                                              ushort* __restrict__ fB) {
  const int bid = blockIdx.x;            // (tap*10+kstep)*16 + nt, 480 total
  const int lane = threadIdx.x;
  const int nt = bid & 15;
  const int tk = bid >> 4;
  const int tap = tk / 10, kstep = tk - tap * 10;
  const int f = nt * 16 + (lane & 15);
  const int kb = kstep * 32 + (lane >> 4) * 8;
  uint p[4];
#pragma unroll
  for (int h = 0; h < 4; ++h) {
    int d0 = kb + h * 2, d1 = kb + h * 2 + 1;
    float v0 = (d0 < 300) ? filters[(size_t)f * 900 + tap * 300 + d0] : 0.f;
    float v1 = (d1 < 300) ? filters[(size_t)f * 900 + tap * 300 + d1] : 0.f;
    p[h] = (uint)bf16rne(v0) | ((uint)bf16rne(v1) << 16);
  }
  uint4* dst = (uint4*)(fB + ((size_t)bid * 64 + lane) * 8);
  *dst = make_uint4(p[0], p[1], p[2], p[3]);
}

// Conv body (r10/r11-proven, verbatim): one sequence, 4 waves, batched gather,
// emits blobA/blobC sim fragments + rcpA/rcpC row norms.
template<int L, int MT, int ROWS_ST>
__device__ __forceinline__ void conv_body(int seq,
                                          const int* __restrict__ tokens,
                                          const float* __restrict__ embeds,
                                          const ushort* __restrict__ fB,
                                          ushort* __restrict__ blobA,
                                          ushort* __restrict__ blobC,
                                          float* __restrict__ rcpA,
                                          float* __restrict__ rcpC,
                                          ushort* xs, int* tok) {
  constexpr int GITEMS = ROWS_ST * 80;                 // float4 slots
  constexpr int GIT = (GITEMS + 255) / 256;            // per-thread trips
  const int tid = threadIdx.x;

  if (tid < L) tok[tid] = tokens[(size_t)seq * L + tid];
  __syncthreads();

  // ---- batched issue-early/write-late gather: 8 independent loads in flight ----
  for (int base = 0; base < GIT; base += 8) {
    float4 gv[8];
#pragma unroll
    for (int u = 0; u < 8; ++u) {
      int it = base + u;
      if (it < GIT) {
        int idx = it * 256 + tid;
        int row = idx / 80;
        int d = (idx - row * 80) * 4;
        bool ok = (idx < GITEMS) && (row < L) && (d < 300);
        int tr = (row < L) ? row : 0;
        const float4* p = (const float4*)(embeds + (size_t)tok[tr] * 300 + (ok ? d : 0));
        float4 z = make_float4(0.f, 0.f, 0.f, 0.f);
        gv[u] = ok ? *p : z;
      }
    }
#pragma unroll
    for (int u = 0; u < 8; ++u) {
      int it = base + u;
      if (it < GIT) {
        int idx = it * 256 + tid;
        if (idx < GITEMS) {
          int row = idx / 80;
          int d = (idx - row * 80) * 4;
          int flat = row * 320 + d;
          *(uint2*)(xs + (flat ^ ((row & 7) << 3))) =
              make_uint2(pack2(gv[u].x, gv[u].y), pack2(gv[u].z, gv[u].w));
        }
      }
    }
  }
  __syncthreads();

  const int wv = tid >> 6, lane = tid & 63;
  const int lr = lane & 15, lh = lane >> 4;

  // ---- pack blobA (phase-0 sim fragments) ----
  for (int t = wv; t < 10 * MT; t += 4) {
    int kstep = t / MT, tile = t - kstep * MT;
    int row = tile * 16 + lr;
    int flat = row * 320 + kstep * 32 + lh * 8;
    s16x8 v = *(const s16x8*)(xs + (flat ^ ((row & 7) << 3)));
    *(s16x8*)(blobA + ((((size_t)seq * 10 + kstep) * MT + tile) * 64 + lane) * 8) = v;
  }
  // ---- phase-0 norms ----
  if (tid < L) {
    int row = tid;
    float s = 0.f;
    for (int c = 0; c < 40; ++c) {
      int flat = row * 320 + c * 8;
      s16x8 v = *(const s16x8*)(xs + (flat ^ ((row & 7) << 3)));
#pragma unroll
      for (int i = 0; i < 8; ++i) { float f = ubf(v[i]); s += f * f; }
    }
    rcpA[(size_t)seq * L + row] = (s > 0.f) ? rsqrtf(s) : 0.f;
  }

  // ---- conv MFMA ----
  f32x4 acc[MT][4];
#pragma unroll
  for (int mt = 0; mt < MT; ++mt)
#pragma unroll
    for (int n = 0; n < 4; ++n)
#pragma unroll
      for (int r = 0; r < 4; ++r) acc[mt][n][r] = 0.f;

  const s16x8* fBv = (const s16x8*)fB;
  for (int kstep = 0; kstep < 10; ++kstep) {
#pragma unroll
    for (int tap = 0; tap < 3; ++tap) {
      s16x8 b[4];
#pragma unroll
      for (int n = 0; n < 4; ++n)
        b[n] = fBv[((size_t)((tap * 10 + kstep) * 16 + (wv * 4 + n))) * 64 + lane];
#pragma unroll
      for (int mt = 0; mt < MT; ++mt) {
        int row = mt * 16 + lr + tap;
        int flat = row * 320 + kstep * 32 + lh * 8;
        s16x8 a = *(const s16x8*)(xs + (flat ^ ((row & 7) << 3)));
#pragma unroll
        for (int n = 0; n < 4; ++n)
          acc[mt][n] = __builtin_amdgcn_mfma_f32_16x16x32_bf16(a, b[n], acc[mt][n], 0, 0, 0);
      }
    }
  }
  __syncthreads();   // all xs readers (blobA, norms, MFMA A-frags) done

  // ---- write conv output back into xs as bf16 (rows j<L, cols<256).
  //      rows >= L keep staged zeros; cols 256.. never read by blobC (KS=8).
#pragma unroll
  for (int mt = 0; mt < MT; ++mt)
#pragma unroll
    for (int n = 0; n < 4; ++n)
#pragma unroll
      for (int r = 0; r < 4; ++r) {
        int j = mt * 16 + lh * 4 + r;
        if (j < L) {
          int f = wv * 64 + n * 16 + lr;
          int flat = j * 320 + f;
          xs[flat ^ ((j & 7) << 3)] = bf16rne(acc[mt][n][r]);
        }
      }
  __syncthreads();

  // ---- pack blobC (phase-1 sim fragments, KS=8) ----
  for (int t = wv; t < 8 * MT; t += 4) {
    int kstep = t / MT, tile = t - kstep * MT;
    int row = tile * 16 + lr;
    int flat = row * 320 + kstep * 32 + lh * 8;
    s16x8 v = *(const s16x8*)(xs + (flat ^ ((row & 7) << 3)));
    *(s16x8*)(blobC + ((((size_t)seq * 8 + kstep) * MT + tile) * 64 + lane) * 8) = v;
  }
  // ---- phase-1 norms (cols 0..255) ----
  if (tid < L) {
    int row = tid;
    float s = 0.f;
    for (int c = 0; c < 32; ++c) {
      int flat = row * 320 + c * 8;
      s16x8 v = *(const s16x8*)(xs + (flat ^ ((row & 7) << 3)));
#pragma unroll
      for (int i = 0; i < 8; ++i) { float f = ubf(v[i]); s += f * f; }
    }
    rcpC[(size_t)seq * L + row] = (s > 0.f) ? rsqrtf(s) : 0.f;
  }
}

// Merged conv dispatch: blocks [0,1024) = sentence side (L=40), [1024,1056) =
// question side (L=30). Question blocks hide in the sentence occupancy shadow.
__global__ __launch_bounds__(256) void k_conv_all(const int* __restrict__ question,
                                                  const int* __restrict__ sentences,
                                                  const float* __restrict__ embeds,
                                                  const ushort* __restrict__ fB,
                                                  ushort* __restrict__ seb,
                                                  ushort* __restrict__ scb,
                                                  ushort* __restrict__ qeb,
                                                  ushort* __restrict__ qcb,
                                                  float* __restrict__ rs0,
                                                  float* __restrict__ rs1,
                                                  float* __restrict__ rq0,
                                                  float* __restrict__ rq1) {
  __shared__ __align__(16) ushort xs[50 * 320];   // sized for the L=40 path (32 KB)
  __shared__ int tok[64];
  const int bid = blockIdx.x;
  if (bid < 1024) {
    conv_body<40, 3, 50>(bid, sentences, embeds, fB, seb, scb, rs0, rs1, xs, tok);
  } else {
    conv_body<30, 2, 34>(bid - 1024, question, embeds, fB, qeb, qcb, rq0, rq1, xs, tok);
  }
}

// One block per (b,s): MFMA sims from pre-packed fragment blobs, top-5 pooling,
// sigmoid, mean -> out[1+bs]. The LAST block (device-scope counter) then computes
// the losses + doc_em exactly as the old k_loss (bit-identical order).
__global__ __launch_bounds__(256, 6) void k_sim(const float* __restrict__ oneh,
                                                const ushort* __restrict__ qeb,
                                                const ushort* __restrict__ seb,
                                                const ushort* __restrict__ qcb,
                                                const ushort* __restrict__ scb,
                                                const float* __restrict__ rq0,
                                                const float* __restrict__ rs0,
                                                const float* __restrict__ rq1,
                                                const float* __restrict__ rs1,
                                                const float* __restrict__ lin_w,
                                                const float* __restrict__ lin_b,
                                                const int* __restrict__ tsent,
                                                const int* __restrict__ tdoc,
                                                unsigned int* __restrict__ counter,
                                                float* __restrict__ out) {
  const int bs = blockIdx.x;
  const int b = bs >> 5;
  const int tid = threadIdx.x;
  const int wv = tid >> 6, lane = tid & 63;
  const int lr = lane & 15, lh = lane >> 4;

  __shared__ float simb[2][30][49];
  __shared__ float ohl[30 * 41];
  __shared__ float rQ[2][30], rS[2][40];
  __shared__ float feats[30][6];
  __shared__ float lo[30];
  __shared__ float red[256];
  __shared__ float sent_loss_sh;
  __shared__ int lastFlag;

  if (tid < 30) rQ[0][tid] = rq0[b * 30 + tid];
  else if (tid < 60) rQ[1][tid - 30] = rq1[b * 30 + (tid - 30)];
  else if (tid < 100) rS[0][tid - 60] = rs0[(size_t)bs * 40 + (tid - 60)];
  else if (tid < 140) rS[1][tid - 100] = rs1[(size_t)bs * 40 + (tid - 100)];
  {
    const float* og = oneh + (size_t)bs * 1200;
    for (int i = tid; i < 1200; i += 256) {
      int q = i / 40, l = i - q * 40;
      ohl[q * 41 + l] = og[i];
    }
  }
  __syncthreads();

  // 6 wave-tasks: (ph, nt); fragments loaded straight from global (coalesced 1KB/wave)
  for (int task = wv; task < 6; task += 4) {
    int ph = task / 3, nt = task - ph * 3;
    int KS = ph ? 8 : 10;
    const ushort* Ab = ph ? (qcb + (size_t)b * 8 * 2 * 512) : (qeb + (size_t)b * 10 * 2 * 512);
    const ushort* Bb = ph ? (scb + (size_t)bs * 8 * 3 * 512) : (seb + (size_t)bs * 10 * 3 * 512);
    f32x4 acc0 = {0.f, 0.f, 0.f, 0.f};
    f32x4 acc1 = {0.f, 0.f, 0.f, 0.f};
    for (int k = 0; k < KS; ++k) {
      s16x8 bf = *(const s16x8*)(Bb + ((size_t)(k * 3 + nt) * 64 + lane) * 8);
      s16x8 a0 = *(const s16x8*)(Ab + ((size_t)(k * 2 + 0) * 64 + lane) * 8);
      s16x8 a1 = *(const s16x8*)(Ab + ((size_t)(k * 2 + 1) * 64 + lane) * 8);
      acc0 = __builtin_amdgcn_mfma_f32_16x16x32_bf16(a0, bf, acc0, 0, 0, 0);
      acc1 = __builtin_amdgcn_mfma_f32_16x16x32_bf16(a1, bf, acc1, 0, 0, 0);
    }
    int l = nt * 16 + lr;
    if (l < 40) {
#pragma unroll
      for (int r = 0; r < 4; ++r) {
        int q0 = lh * 4 + r;                       // < 16
        simb[ph][q0][l] = acc0[r] * rQ[ph][q0] * rS[ph][l];
        int q1 = 16 + lh * 4 + r;
        if (q1 < 30) simb[ph][q1][l] = acc1[r] * rQ[ph][q1] * rS[ph][l];
      }
    }
  }
  __syncthreads();

  // duplicate-safe top-5 pooling on 90 threads
  if (tid < 90) {
    const int m = tid / 30, q = tid - m * 30;
    const float* row = (m == 0) ? &simb[0][q][0] : (m == 1) ? &simb[1][q][0] : (ohl + q * 41);
    float thr = 3.4e38f;
    int got = 0;
    float sum = 0.f, maxv = 0.f;
    while (got < 5) {
      float mx = -3.4e38f;
      int c = 0;
      for (int l = 0; l < 40; ++l) {
        float v = row[l];
        if (v < thr) {
          if (v > mx) { mx = v; c = 1; }
          else if (v == mx) { c++; }
        }
      }
      if (c == 0) break;  // safety: never hang
      if (got == 0) maxv = mx;
      int take = (c < 5 - got) ? c : (5 - got);
      sum += mx * (float)take;
      got += take;
      thr = mx;
    }
    feats[q][m * 2 + 0] = maxv;
    feats[q][m * 2 + 1] = sum * 0.2f;
  }
  __syncthreads();
  if (tid < 30) {
    float z = lin_b[0];
#pragma unroll
    for (int i = 0; i < 6; ++i) z += feats[tid][i] * lin_w[i];
    lo[tid] = 1.0f / (1.0f + expf(-z));
  }
  __syncthreads();
  if (tid == 0) {
    float sum = 0.f;
    for (int q = 0; q < 30; ++q) sum += lo[q];
    out[1 + bs] = sum * (1.0f / 30.0f);
    __threadfence();                               // device-scope release
    unsigned int old = atomicAdd(counter, 1u);     // device-scope (m20)
    lastFlag = (old == 1023u) ? 1 : 0;
  }
  __syncthreads();
  if (!lastFlag) return;

  // ---- last block: losses + doc_em (identical order to old k_loss) ----
  __threadfence();                                 // device-scope acquire
  {
    float local = 0.f;
    for (int i = tid; i < 1024; i += 256) {
      float p = out[1 + i];
      float t = (float)tsent[i];
      float lp = fmaxf(logf(p), -100.f);
      float l1 = fmaxf(logf(1.f - p), -100.f);
      local += -(t * lp + (1.f - t) * l1);
    }
    red[tid] = local;
    __syncthreads();
    for (int off = 128; off > 0; off >>= 1) {
      if (tid < off) red[tid] += red[tid + off];
      __syncthreads();
    }
    if (tid == 0) sent_loss_sh = red[0] * (1.0f / 1024.0f);
    __syncthreads();
    float dterm = 0.f;
    if (tid < 32) {
      float mx = out[1 + tid * 32];
      for (int s2 = 1; s2 < 32; ++s2) mx = fmaxf(mx, out[1 + tid * 32 + s2]);
      out[1025 + tid] = mx;
      float t = (float)tdoc[tid];
      float lp = fmaxf(logf(mx), -100.f);
      float l1 = fmaxf(logf(1.f - mx), -100.f);
      dterm = -(t * lp + (1.f - t) * l1);
    }
    red[tid] = dterm;
    __syncthreads();
    for (int off = 128; off > 0; off >>= 1) {
      if (tid < off) red[tid] += red[tid + off];
      __syncthreads();
    }
    if (tid == 0) out[0] = 0.5f * (sent_loss_sh + red[0] * (1.0f / 32.0f));
  }
}

extern "C" void kernel_launch(void* const* d_in, const int* in_sizes, int n_in,
                              void* d_out, int out_size, void* d_ws, size_t ws_size,
                              hipStream_t stream) {
  const int*   question     = (const int*)d_in[0];
  const int*   sentences    = (const int*)d_in[1];
  const int*   target_sents = (const int*)d_in[2];
  const int*   target_docs  = (const int*)d_in[3];
  const float* oneh         = (const float*)d_in[4];
  const float* embeds       = (const float*)d_in[5];
  const float* filters      = (const float*)d_in[6];
  const float* lin_w        = (const float*)d_in[7];
  const float* lin_b        = (const float*)d_in[8];
  float* out = (float*)d_out;

  // workspace layout:
  ushort* fB  = (ushort*)d_ws;             // 480*64*8        = 245,760 ush (491.5 KB)
  ushort* seb = fB  + 245760;              // 1024*10*3*512   = 15,728,640 ush (30 MB)
  ushort* scb = seb + 15728640;            // 1024*8*3*512    = 12,582,912 ush (24 MB)
  ushort* qeb = scb + 12582912;            // 32*10*2*512     = 327,680 ush
  ushort* qcb = qeb + 327680;              // 32*8*2*512      = 262,144 ush
  float*  rs0 = (float*)(qcb + 262144);    // 1024*40
  float*  rs1 = rs0 + 40960;               // 1024*40
  float*  rq0 = rs1 + 40960;               // 32*30
  float*  rq1 = rq0 + 960;                 // 32*30
  unsigned int* counter = (unsigned int*)(rq1 + 960);

  hipMemsetAsync(counter, 0, sizeof(unsigned int), stream);
  k_prepB<<<480, 64, 0, stream>>>(filters, fB);
  k_conv_all<<<1056, 256, 0, stream>>>(question, sentences, embeds, fB,
                                       seb, scb, qeb, qcb, rs0, rs1, rq0, rq1);
  k_sim<<<1024, 256, 0, stream>>>(oneh, qeb, seb, qcb, scb, rq0, rs0, rq1, rs1,
                                  lin_w, lin_b, target_sents, target_docs, counter, out);
}

// Round 14
// 111.649 us; speedup vs baseline: 1.1170x; 1.0252x over previous
//
#include <hip/hip_runtime.h>
#include <math.h>

// B=32, S=32, LQ=30, LS=40, D=300, F=256, FS=3, K=5
// out layout: [0]=total_loss, [1..1024]=sent_output(B,S), [1025..1056]=doc_em(B)

typedef __attribute__((ext_vector_type(4))) float f32x4;
typedef __attribute__((ext_vector_type(8))) short s16x8;

__device__ inline ushort bf16rne(float f) {
  unsigned u = __float_as_uint(f);
  u += 0x7fff + ((u >> 16) & 1);
  return (ushort)(u >> 16);
}
__device__ inline uint pack2(float a, float b) {
  return (uint)bf16rne(a) | ((uint)bf16rne(b) << 16);
}
__device__ inline float ubf(short h) { return __uint_as_float(((uint)(ushort)h) << 16); }

// Pack filters into MFMA B-fragment-major layout. Block 0 lane 0 also resets the
// completion counter used by k_sim's last-block loss fold (stream order makes
// this visible before k_sim starts -> deterministic every call).
__global__ __launch_bounds__(64) void k_prepB(const float* __restrict__ filters,
                                              ushort* __restrict__ fB,
                                              unsigned int* __restrict__ counter) {
  const int bid = blockIdx.x;            // (tap*10+kstep)*16 + nt, 480 total
  const int lane = threadIdx.x;
  if (bid == 0 && lane == 0) *counter = 0u;
  const int nt = bid & 15;
  const int tk = bid >> 4;
  const int tap = tk / 10, kstep = tk - tap * 10;
  const int f = nt * 16 + (lane & 15);
  const int kb = kstep * 32 + (lane >> 4) * 8;
  uint p[4];
#pragma unroll
  for (int h = 0; h < 4; ++h) {
    int d0 = kb + h * 2, d1 = kb + h * 2 + 1;
    float v0 = (d0 < 300) ? filters[(size_t)f * 900 + tap * 300 + d0] : 0.f;
    float v1 = (d1 < 300) ? filters[(size_t)f * 900 + tap * 300 + d1] : 0.f;
    p[h] = (uint)bf16rne(v0) | ((uint)bf16rne(v1) << 16);
  }
  uint4* dst = (uint4*)(fB + ((size_t)bid * 64 + lane) * 8);
  *dst = make_uint4(p[0], p[1], p[2], p[3]);
}

// Conv body (r10/r11-proven, verbatim): one sequence, 4 waves, batched gather,
// emits blobA/blobC sim fragments + rcpA/rcpC row norms.
template<int L, int MT, int ROWS_ST>
__device__ __forceinline__ void conv_body(int seq,
                                          const int* __restrict__ tokens,
                                          const float* __restrict__ embeds,
                                          const ushort* __restrict__ fB,
                                          ushort* __restrict__ blobA,
                                          ushort* __restrict__ blobC,
                                          float* __restrict__ rcpA,
                                          float* __restrict__ rcpC,
                                          ushort* xs, int* tok) {
  constexpr int GITEMS = ROWS_ST * 80;                 // float4 slots
  constexpr int GIT = (GITEMS + 255) / 256;            // per-thread trips
  const int tid = threadIdx.x;

  if (tid < L) tok[tid] = tokens[(size_t)seq * L + tid];
  __syncthreads();

  // ---- batched issue-early/write-late gather: 8 independent loads in flight ----
  for (int base = 0; base < GIT; base += 8) {
    float4 gv[8];
#pragma unroll
    for (int u = 0; u < 8; ++u) {
      int it = base + u;
      if (it < GIT) {
        int idx = it * 256 + tid;
        int row = idx / 80;
        int d = (idx - row * 80) * 4;
        bool ok = (idx < GITEMS) && (row < L) && (d < 300);
        int tr = (row < L) ? row : 0;
        const float4* p = (const float4*)(embeds + (size_t)tok[tr] * 300 + (ok ? d : 0));
        float4 z = make_float4(0.f, 0.f, 0.f, 0.f);
        gv[u] = ok ? *p : z;
      }
    }
#pragma unroll
    for (int u = 0; u < 8; ++u) {
      int it = base + u;
      if (it < GIT) {
        int idx = it * 256 + tid;
        if (idx < GITEMS) {
          int row = idx / 80;
          int d = (idx - row * 80) * 4;
          int flat = row * 320 + d;
          *(uint2*)(xs + (flat ^ ((row & 7) << 3))) =
              make_uint2(pack2(gv[u].x, gv[u].y), pack2(gv[u].z, gv[u].w));
        }
      }
    }
  }
  __syncthreads();

  const int wv = tid >> 6, lane = tid & 63;
  const int lr = lane & 15, lh = lane >> 4;

  // ---- pack blobA (phase-0 sim fragments) ----
  for (int t = wv; t < 10 * MT; t += 4) {
    int kstep = t / MT, tile = t - kstep * MT;
    int row = tile * 16 + lr;
    int flat = row * 320 + kstep * 32 + lh * 8;
    s16x8 v = *(const s16x8*)(xs + (flat ^ ((row & 7) << 3)));
    *(s16x8*)(blobA + ((((size_t)seq * 10 + kstep) * MT + tile) * 64 + lane) * 8) = v;
  }
  // ---- phase-0 norms ----
  if (tid < L) {
    int row = tid;
    float s = 0.f;
    for (int c = 0; c < 40; ++c) {
      int flat = row * 320 + c * 8;
      s16x8 v = *(const s16x8*)(xs + (flat ^ ((row & 7) << 3)));
#pragma unroll
      for (int i = 0; i < 8; ++i) { float f = ubf(v[i]); s += f * f; }
    }
    rcpA[(size_t)seq * L + row] = (s > 0.f) ? rsqrtf(s) : 0.f;
  }

  // ---- conv MFMA ----
  f32x4 acc[MT][4];
#pragma unroll
  for (int mt = 0; mt < MT; ++mt)
#pragma unroll
    for (int n = 0; n < 4; ++n)
#pragma unroll
      for (int r = 0; r < 4; ++r) acc[mt][n][r] = 0.f;

  const s16x8* fBv = (const s16x8*)fB;
  for (int kstep = 0; kstep < 10; ++kstep) {
#pragma unroll
    for (int tap = 0; tap < 3; ++tap) {
      s16x8 b[4];
#pragma unroll
      for (int n = 0; n < 4; ++n)
        b[n] = fBv[((size_t)((tap * 10 + kstep) * 16 + (wv * 4 + n))) * 64 + lane];
#pragma unroll
      for (int mt = 0; mt < MT; ++mt) {
        int row = mt * 16 + lr + tap;
        int flat = row * 320 + kstep * 32 + lh * 8;
        s16x8 a = *(const s16x8*)(xs + (flat ^ ((row & 7) << 3)));
#pragma unroll
        for (int n = 0; n < 4; ++n)
          acc[mt][n] = __builtin_amdgcn_mfma_f32_16x16x32_bf16(a, b[n], acc[mt][n], 0, 0, 0);
      }
    }
  }
  __syncthreads();   // all xs readers (blobA, norms, MFMA A-frags) done

  // ---- write conv output back into xs as bf16 (rows j<L, cols<256).
  //      rows >= L keep staged zeros; cols 256.. never read by blobC (KS=8).
#pragma unroll
  for (int mt = 0; mt < MT; ++mt)
#pragma unroll
    for (int n = 0; n < 4; ++n)
#pragma unroll
      for (int r = 0; r < 4; ++r) {
        int j = mt * 16 + lh * 4 + r;
        if (j < L) {
          int f = wv * 64 + n * 16 + lr;
          int flat = j * 320 + f;
          xs[flat ^ ((j & 7) << 3)] = bf16rne(acc[mt][n][r]);
        }
      }
  __syncthreads();

  // ---- pack blobC (phase-1 sim fragments, KS=8) ----
  for (int t = wv; t < 8 * MT; t += 4) {
    int kstep = t / MT, tile = t - kstep * MT;
    int row = tile * 16 + lr;
    int flat = row * 320 + kstep * 32 + lh * 8;
    s16x8 v = *(const s16x8*)(xs + (flat ^ ((row & 7) << 3)));
    *(s16x8*)(blobC + ((((size_t)seq * 8 + kstep) * MT + tile) * 64 + lane) * 8) = v;
  }
  // ---- phase-1 norms (cols 0..255) ----
  if (tid < L) {
    int row = tid;
    float s = 0.f;
    for (int c = 0; c < 32; ++c) {
      int flat = row * 320 + c * 8;
      s16x8 v = *(const s16x8*)(xs + (flat ^ ((row & 7) << 3)));
#pragma unroll
      for (int i = 0; i < 8; ++i) { float f = ubf(v[i]); s += f * f; }
    }
    rcpC[(size_t)seq * L + row] = (s > 0.f) ? rsqrtf(s) : 0.f;
  }
}

// Merged conv dispatch: blocks [0,1024) = sentence side (L=40), [1024,1056) =
// question side (L=30). Question blocks hide in the sentence occupancy shadow.
__global__ __launch_bounds__(256) void k_conv_all(const int* __restrict__ question,
                                                  const int* __restrict__ sentences,
                                                  const float* __restrict__ embeds,
                                                  const ushort* __restrict__ fB,
                                                  ushort* __restrict__ seb,
                                                  ushort* __restrict__ scb,
                                                  ushort* __restrict__ qeb,
                                                  ushort* __restrict__ qcb,
                                                  float* __restrict__ rs0,
                                                  float* __restrict__ rs1,
                                                  float* __restrict__ rq0,
                                                  float* __restrict__ rq1) {
  __shared__ __align__(16) ushort xs[50 * 320];   // sized for the L=40 path (32 KB)
  __shared__ int tok[64];
  const int bid = blockIdx.x;
  if (bid < 1024) {
    conv_body<40, 3, 50>(bid, sentences, embeds, fB, seb, scb, rs0, rs1, xs, tok);
  } else {
    conv_body<30, 2, 34>(bid - 1024, question, embeds, fB, qeb, qcb, rq0, rq1, xs, tok);
  }
}

// One block per (b,s): MFMA sims from pre-packed fragment blobs, top-5 pooling,
// sigmoid, mean -> out[1+bs]. The LAST block (device-scope counter) then computes
// the losses + doc_em exactly as the old k_loss (bit-identical order).
__global__ __launch_bounds__(256, 6) void k_sim(const float* __restrict__ oneh,
                                                const ushort* __restrict__ qeb,
                                                const ushort* __restrict__ seb,
                                                const ushort* __restrict__ qcb,
                                                const ushort* __restrict__ scb,
                                                const float* __restrict__ rq0,
                                                const float* __restrict__ rs0,
                                                const float* __restrict__ rq1,
                                                const float* __restrict__ rs1,
                                                const float* __restrict__ lin_w,
                                                const float* __restrict__ lin_b,
                                                const int* __restrict__ tsent,
                                                const int* __restrict__ tdoc,
                                                unsigned int* __restrict__ counter,
                                                float* __restrict__ out) {
  const int bs = blockIdx.x;
  const int b = bs >> 5;
  const int tid = threadIdx.x;
  const int wv = tid >> 6, lane = tid & 63;
  const int lr = lane & 15, lh = lane >> 4;

  __shared__ float simb[2][30][49];
  __shared__ float ohl[30 * 41];
  __shared__ float rQ[2][30], rS[2][40];
  __shared__ float feats[30][6];
  __shared__ float lo[30];
  __shared__ float red[256];
  __shared__ float sent_loss_sh;
  __shared__ int lastFlag;

  if (tid < 30) rQ[0][tid] = rq0[b * 30 + tid];
  else if (tid < 60) rQ[1][tid - 30] = rq1[b * 30 + (tid - 30)];
  else if (tid < 100) rS[0][tid - 60] = rs0[(size_t)bs * 40 + (tid - 60)];
  else if (tid < 140) rS[1][tid - 100] = rs1[(size_t)bs * 40 + (tid - 100)];
  {
    const float* og = oneh + (size_t)bs * 1200;
    for (int i = tid; i < 1200; i += 256) {
      int q = i / 40, l = i - q * 40;
      ohl[q * 41 + l] = og[i];
    }
  }
  __syncthreads();

  // 6 wave-tasks: (ph, nt); fragments loaded straight from global (coalesced 1KB/wave)
  for (int task = wv; task < 6; task += 4) {
    int ph = task / 3, nt = task - ph * 3;
    int KS = ph ? 8 : 10;
    const ushort* Ab = ph ? (qcb + (size_t)b * 8 * 2 * 512) : (qeb + (size_t)b * 10 * 2 * 512);
    const ushort* Bb = ph ? (scb + (size_t)bs * 8 * 3 * 512) : (seb + (size_t)bs * 10 * 3 * 512);
    f32x4 acc0 = {0.f, 0.f, 0.f, 0.f};
    f32x4 acc1 = {0.f, 0.f, 0.f, 0.f};
    for (int k = 0; k < KS; ++k) {
      s16x8 bf = *(const s16x8*)(Bb + ((size_t)(k * 3 + nt) * 64 + lane) * 8);
      s16x8 a0 = *(const s16x8*)(Ab + ((size_t)(k * 2 + 0) * 64 + lane) * 8);
      s16x8 a1 = *(const s16x8*)(Ab + ((size_t)(k * 2 + 1) * 64 + lane) * 8);
      acc0 = __builtin_amdgcn_mfma_f32_16x16x32_bf16(a0, bf, acc0, 0, 0, 0);
      acc1 = __builtin_amdgcn_mfma_f32_16x16x32_bf16(a1, bf, acc1, 0, 0, 0);
    }
    int l = nt * 16 + lr;
    if (l < 40) {
#pragma unroll
      for (int r = 0; r < 4; ++r) {
        int q0 = lh * 4 + r;                       // < 16
        simb[ph][q0][l] = acc0[r] * rQ[ph][q0] * rS[ph][l];
        int q1 = 16 + lh * 4 + r;
        if (q1 < 30) simb[ph][q1][l] = acc1[r] * rQ[ph][q1] * rS[ph][l];
      }
    }
  }
  __syncthreads();

  // duplicate-safe top-5 pooling on 90 threads
  if (tid < 90) {
    const int m = tid / 30, q = tid - m * 30;
    const float* row = (m == 0) ? &simb[0][q][0] : (m == 1) ? &simb[1][q][0] : (ohl + q * 41);
    float thr = 3.4e38f;
    int got = 0;
    float sum = 0.f, maxv = 0.f;
    while (got < 5) {
      float mx = -3.4e38f;
      int c = 0;
      for (int l = 0; l < 40; ++l) {
        float v = row[l];
        if (v < thr) {
          if (v > mx) { mx = v; c = 1; }
          else if (v == mx) { c++; }
        }
      }
      if (c == 0) break;  // safety: never hang
      if (got == 0) maxv = mx;
      int take = (c < 5 - got) ? c : (5 - got);
      sum += mx * (float)take;
      got += take;
      thr = mx;
    }
    feats[q][m * 2 + 0] = maxv;
    feats[q][m * 2 + 1] = sum * 0.2f;
  }
  __syncthreads();
  if (tid < 30) {
    float z = lin_b[0];
#pragma unroll
    for (int i = 0; i < 6; ++i) z += feats[tid][i] * lin_w[i];
    lo[tid] = 1.0f / (1.0f + expf(-z));
  }
  __syncthreads();
  if (tid == 0) {
    float sum = 0.f;
    for (int q = 0; q < 30; ++q) sum += lo[q];
    out[1 + bs] = sum * (1.0f / 30.0f);
    __threadfence();                               // device-scope release
    unsigned int old = atomicAdd(counter, 1u);     // device-scope (m20)
    lastFlag = (old == 1023u) ? 1 : 0;
  }
  __syncthreads();
  if (!lastFlag) return;

  // ---- last block: losses + doc_em (identical order to old k_loss) ----
  __threadfence();                                 // device-scope acquire
  {
    float local = 0.f;
    for (int i = tid; i < 1024; i += 256) {
      float p = out[1 + i];
      float t = (float)tsent[i];
      float lp = fmaxf(logf(p), -100.f);
      float l1 = fmaxf(logf(1.f - p), -100.f);
      local += -(t * lp + (1.f - t) * l1);
    }
    red[tid] = local;
    __syncthreads();
    for (int off = 128; off > 0; off >>= 1) {
      if (tid < off) red[tid] += red[tid + off];
      __syncthreads();
    }
    if (tid == 0) sent_loss_sh = red[0] * (1.0f / 1024.0f);
    __syncthreads();
    float dterm = 0.f;
    if (tid < 32) {
      float mx = out[1 + tid * 32];
      for (int s2 = 1; s2 < 32; ++s2) mx = fmaxf(mx, out[1 + tid * 32 + s2]);
      out[1025 + tid] = mx;
      float t = (float)tdoc[tid];
      float lp = fmaxf(logf(mx), -100.f);
      float l1 = fmaxf(logf(1.f - mx), -100.f);
      dterm = -(t * lp + (1.f - t) * l1);
    }
    red[tid] = dterm;
    __syncthreads();
    for (int off = 128; off > 0; off >>= 1) {
      if (tid < off) red[tid] += red[tid + off];
      __syncthreads();
    }
    if (tid == 0) out[0] = 0.5f * (sent_loss_sh + red[0] * (1.0f / 32.0f));
  }
}

extern "C" void kernel_launch(void* const* d_in, const int* in_sizes, int n_in,
                              void* d_out, int out_size, void* d_ws, size_t ws_size,
                              hipStream_t stream) {
  const int*   question     = (const int*)d_in[0];
  const int*   sentences    = (const int*)d_in[1];
  const int*   target_sents = (const int*)d_in[2];
  const int*   target_docs  = (const int*)d_in[3];
  const float* oneh         = (const float*)d_in[4];
  const float* embeds       = (const float*)d_in[5];
  const float* filters      = (const float*)d_in[6];
  const float* lin_w        = (const float*)d_in[7];
  const float* lin_b        = (const float*)d_in[8];
  float* out = (float*)d_out;

  // workspace layout:
  ushort* fB  = (ushort*)d_ws;             // 480*64*8        = 245,760 ush (491.5 KB)
  ushort* seb = fB  + 245760;              // 1024*10*3*512   = 15,728,640 ush (30 MB)
  ushort* scb = seb + 15728640;            // 1024*8*3*512    = 12,582,912 ush (24 MB)
  ushort* qeb = scb + 12582912;            // 32*10*2*512     = 327,680 ush
  ushort* qcb = qeb + 327680;              // 32*8*2*512      = 262,144 ush
  float*  rs0 = (float*)(qcb + 262144);    // 1024*40
  float*  rs1 = rs0 + 40960;               // 1024*40
  float*  rq0 = rs1 + 40960;               // 32*30
  float*  rq1 = rq0 + 960;                 // 32*30
  unsigned int* counter = (unsigned int*)(rq1 + 960);

  k_prepB<<<480, 64, 0, stream>>>(filters, fB, counter);
  k_conv_all<<<1056, 256, 0, stream>>>(question, sentences, embeds, fB,
                                       seb, scb, qeb, qcb, rs0, rs1, rq0, rq1);
  k_sim<<<1024, 256, 0, stream>>>(oneh, qeb, seb, qcb, scb, rq0, rs0, rq1, rs1,
                                  lin_w, lin_b, target_sents, target_docs, counter, out);
}

// Round 15
// 94.724 us; speedup vs baseline: 1.3166x; 1.1787x over previous
//
#include <hip/hip_runtime.h>
#include <math.h>

// B=32, S=32, LQ=30, LS=40, D=300, F=256, FS=3, K=5
// out layout: [0]=total_loss, [1..1024]=sent_output(B,S), [1025..1056]=doc_em(B)

typedef __attribute__((ext_vector_type(4))) float f32x4;
typedef __attribute__((ext_vector_type(8))) short s16x8;

__device__ inline ushort bf16rne(float f) {
  unsigned u = __float_as_uint(f);
  u += 0x7fff + ((u >> 16) & 1);
  return (ushort)(u >> 16);
}
__device__ inline uint pack2(float a, float b) {
  return (uint)bf16rne(a) | ((uint)bf16rne(b) << 16);
}
__device__ inline float ubf(short h) { return __uint_as_float(((uint)(ushort)h) << 16); }

// Pack filters into MFMA B-fragment-major layout:
// fB[((tap*10+kstep)*16 + nt)*64 + lane][8] ; B[k][col]: col=lane&15, k=(lane>>4)*8+i
__global__ __launch_bounds__(64) void k_prepB(const float* __restrict__ filters,
                                              ushort* __restrict__ fB) {
  const int bid = blockIdx.x;            // (tap*10+kstep)*16 + nt, 480 total
  const int lane = threadIdx.x;
  const int nt = bid & 15;
  const int tk = bid >> 4;
  const int tap = tk / 10, kstep = tk - tap * 10;
  const int f = nt * 16 + (lane & 15);
  const int kb = kstep * 32 + (lane >> 4) * 8;
  uint p[4];
#pragma unroll
  for (int h = 0; h < 4; ++h) {
    int d0 = kb + h * 2, d1 = kb + h * 2 + 1;
    float v0 = (d0 < 300) ? filters[(size_t)f * 900 + tap * 300 + d0] : 0.f;
    float v1 = (d1 < 300) ? filters[(size_t)f * 900 + tap * 300 + d1] : 0.f;
    p[h] = (uint)bf16rne(v0) | ((uint)bf16rne(v1) << 16);
  }
  uint4* dst = (uint4*)(fB + ((size_t)bid * 64 + lane) * 8);
  *dst = make_uint4(p[0], p[1], p[2], p[3]);
}

// Conv body (r10/r11-proven, verbatim): one sequence, 4 waves, batched gather,
// emits blobA/blobC sim fragments + rcpA/rcpC row norms.
template<int L, int MT, int ROWS_ST>
__device__ __forceinline__ void conv_body(int seq,
                                          const int* __restrict__ tokens,
                                          const float* __restrict__ embeds,
                                          const ushort* __restrict__ fB,
                                          ushort* __restrict__ blobA,
                                          ushort* __restrict__ blobC,
                                          float* __restrict__ rcpA,
                                          float* __restrict__ rcpC,
                                          ushort* xs, int* tok) {
  constexpr int GITEMS = ROWS_ST * 80;                 // float4 slots
  constexpr int GIT = (GITEMS + 255) / 256;            // per-thread trips
  const int tid = threadIdx.x;

  if (tid < L) tok[tid] = tokens[(size_t)seq * L + tid];
  __syncthreads();

  // ---- batched issue-early/write-late gather: 8 independent loads in flight ----
  for (int base = 0; base < GIT; base += 8) {
    float4 gv[8];
#pragma unroll
    for (int u = 0; u < 8; ++u) {
      int it = base + u;
      if (it < GIT) {
        int idx = it * 256 + tid;
        int row = idx / 80;
        int d = (idx - row * 80) * 4;
        bool ok = (idx < GITEMS) && (row < L) && (d < 300);
        int tr = (row < L) ? row : 0;
        const float4* p = (const float4*)(embeds + (size_t)tok[tr] * 300 + (ok ? d : 0));
        float4 z = make_float4(0.f, 0.f, 0.f, 0.f);
        gv[u] = ok ? *p : z;
      }
    }
#pragma unroll
    for (int u = 0; u < 8; ++u) {
      int it = base + u;
      if (it < GIT) {
        int idx = it * 256 + tid;
        if (idx < GITEMS) {
          int row = idx / 80;
          int d = (idx - row * 80) * 4;
          int flat = row * 320 + d;
          *(uint2*)(xs + (flat ^ ((row & 7) << 3))) =
              make_uint2(pack2(gv[u].x, gv[u].y), pack2(gv[u].z, gv[u].w));
        }
      }
    }
  }
  __syncthreads();

  const int wv = tid >> 6, lane = tid & 63;
  const int lr = lane & 15, lh = lane >> 4;

  // ---- pack blobA (phase-0 sim fragments) ----
  for (int t = wv; t < 10 * MT; t += 4) {
    int kstep = t / MT, tile = t - kstep * MT;
    int row = tile * 16 + lr;
    int flat = row * 320 + kstep * 32 + lh * 8;
    s16x8 v = *(const s16x8*)(xs + (flat ^ ((row & 7) << 3)));
    *(s16x8*)(blobA + ((((size_t)seq * 10 + kstep) * MT + tile) * 64 + lane) * 8) = v;
  }
  // ---- phase-0 norms ----
  if (tid < L) {
    int row = tid;
    float s = 0.f;
    for (int c = 0; c < 40; ++c) {
      int flat = row * 320 + c * 8;
      s16x8 v = *(const s16x8*)(xs + (flat ^ ((row & 7) << 3)));
#pragma unroll
      for (int i = 0; i < 8; ++i) { float f = ubf(v[i]); s += f * f; }
    }
    rcpA[(size_t)seq * L + row] = (s > 0.f) ? rsqrtf(s) : 0.f;
  }

  // ---- conv MFMA ----
  f32x4 acc[MT][4];
#pragma unroll
  for (int mt = 0; mt < MT; ++mt)
#pragma unroll
    for (int n = 0; n < 4; ++n)
#pragma unroll
      for (int r = 0; r < 4; ++r) acc[mt][n][r] = 0.f;

  const s16x8* fBv = (const s16x8*)fB;
  for (int kstep = 0; kstep < 10; ++kstep) {
#pragma unroll
    for (int tap = 0; tap < 3; ++tap) {
      s16x8 b[4];
#pragma unroll
      for (int n = 0; n < 4; ++n)
        b[n] = fBv[((size_t)((tap * 10 + kstep) * 16 + (wv * 4 + n))) * 64 + lane];
#pragma unroll
      for (int mt = 0; mt < MT; ++mt) {
        int row = mt * 16 + lr + tap;
        int flat = row * 320 + kstep * 32 + lh * 8;
        s16x8 a = *(const s16x8*)(xs + (flat ^ ((row & 7) << 3)));
#pragma unroll
        for (int n = 0; n < 4; ++n)
          acc[mt][n] = __builtin_amdgcn_mfma_f32_16x16x32_bf16(a, b[n], acc[mt][n], 0, 0, 0);
      }
    }
  }
  __syncthreads();   // all xs readers (blobA, norms, MFMA A-frags) done

  // ---- write conv output back into xs as bf16 (rows j<L, cols<256).
  //      rows >= L keep staged zeros; cols 256.. never read by blobC (KS=8).
#pragma unroll
  for (int mt = 0; mt < MT; ++mt)
#pragma unroll
    for (int n = 0; n < 4; ++n)
#pragma unroll
      for (int r = 0; r < 4; ++r) {
        int j = mt * 16 + lh * 4 + r;
        if (j < L) {
          int f = wv * 64 + n * 16 + lr;
          int flat = j * 320 + f;
          xs[flat ^ ((j & 7) << 3)] = bf16rne(acc[mt][n][r]);
        }
      }
  __syncthreads();

  // ---- pack blobC (phase-1 sim fragments, KS=8) ----
  for (int t = wv; t < 8 * MT; t += 4) {
    int kstep = t / MT, tile = t - kstep * MT;
    int row = tile * 16 + lr;
    int flat = row * 320 + kstep * 32 + lh * 8;
    s16x8 v = *(const s16x8*)(xs + (flat ^ ((row & 7) << 3)));
    *(s16x8*)(blobC + ((((size_t)seq * 8 + kstep) * MT + tile) * 64 + lane) * 8) = v;
  }
  // ---- phase-1 norms (cols 0..255) ----
  if (tid < L) {
    int row = tid;
    float s = 0.f;
    for (int c = 0; c < 32; ++c) {
      int flat = row * 320 + c * 8;
      s16x8 v = *(const s16x8*)(xs + (flat ^ ((row & 7) << 3)));
#pragma unroll
      for (int i = 0; i < 8; ++i) { float f = ubf(v[i]); s += f * f; }
    }
    rcpC[(size_t)seq * L + row] = (s > 0.f) ? rsqrtf(s) : 0.f;
  }
}

// Merged conv dispatch: blocks [0,1024) = sentence side (L=40), [1024,1056) =
// question side (L=30). Question blocks hide in the sentence occupancy shadow.
__global__ __launch_bounds__(256) void k_conv_all(const int* __restrict__ question,
                                                  const int* __restrict__ sentences,
                                                  const float* __restrict__ embeds,
                                                  const ushort* __restrict__ fB,
                                                  ushort* __restrict__ seb,
                                                  ushort* __restrict__ scb,
                                                  ushort* __restrict__ qeb,
                                                  ushort* __restrict__ qcb,
                                                  float* __restrict__ rs0,
                                                  float* __restrict__ rs1,
                                                  float* __restrict__ rq0,
                                                  float* __restrict__ rq1) {
  __shared__ __align__(16) ushort xs[50 * 320];   // sized for the L=40 path (32 KB)
  __shared__ int tok[64];
  const int bid = blockIdx.x;
  if (bid < 1024) {
    conv_body<40, 3, 50>(bid, sentences, embeds, fB, seb, scb, rs0, rs1, xs, tok);
  } else {
    conv_body<30, 2, 34>(bid - 1024, question, embeds, fB, qeb, qcb, rq0, rq1, xs, tok);
  }
}

// One block per (b,s): MFMA sims from pre-packed fragment blobs (register-direct),
// then duplicate-safe top-5 pooling + sigmoid + mean.  (round-6/10/11 proven)
__global__ __launch_bounds__(256, 6) void k_sim(const float* __restrict__ oneh,
                                                const ushort* __restrict__ qeb,
                                                const ushort* __restrict__ seb,
                                                const ushort* __restrict__ qcb,
                                                const ushort* __restrict__ scb,
                                                const float* __restrict__ rq0,
                                                const float* __restrict__ rs0,
                                                const float* __restrict__ rq1,
                                                const float* __restrict__ rs1,
                                                const float* __restrict__ lin_w,
                                                const float* __restrict__ lin_b,
                                                float* __restrict__ out) {
  const int bs = blockIdx.x;
  const int b = bs >> 5;
  const int tid = threadIdx.x;
  const int wv = tid >> 6, lane = tid & 63;
  const int lr = lane & 15, lh = lane >> 4;

  __shared__ float simb[2][30][49];
  __shared__ float ohl[30 * 41];
  __shared__ float rQ[2][30], rS[2][40];
  __shared__ float feats[30][6];
  __shared__ float lo[30];

  if (tid < 30) rQ[0][tid] = rq0[b * 30 + tid];
  else if (tid < 60) rQ[1][tid - 30] = rq1[b * 30 + (tid - 30)];
  else if (tid < 100) rS[0][tid - 60] = rs0[(size_t)bs * 40 + (tid - 60)];
  else if (tid < 140) rS[1][tid - 100] = rs1[(size_t)bs * 40 + (tid - 100)];
  {
    const float* og = oneh + (size_t)bs * 1200;
    for (int i = tid; i < 1200; i += 256) {
      int q = i / 40, l = i - q * 40;
      ohl[q * 41 + l] = og[i];
    }
  }
  __syncthreads();

  // 6 wave-tasks: (ph, nt); fragments loaded straight from global (coalesced 1KB/wave)
  for (int task = wv; task < 6; task += 4) {
    int ph = task / 3, nt = task - ph * 3;
    int KS = ph ? 8 : 10;
    const ushort* Ab = ph ? (qcb + (size_t)b * 8 * 2 * 512) : (qeb + (size_t)b * 10 * 2 * 512);
    const ushort* Bb = ph ? (scb + (size_t)bs * 8 * 3 * 512) : (seb + (size_t)bs * 10 * 3 * 512);
    f32x4 acc0 = {0.f, 0.f, 0.f, 0.f};
    f32x4 acc1 = {0.f, 0.f, 0.f, 0.f};
    for (int k = 0; k < KS; ++k) {
      s16x8 bf = *(const s16x8*)(Bb + ((size_t)(k * 3 + nt) * 64 + lane) * 8);
      s16x8 a0 = *(const s16x8*)(Ab + ((size_t)(k * 2 + 0) * 64 + lane) * 8);
      s16x8 a1 = *(const s16x8*)(Ab + ((size_t)(k * 2 + 1) * 64 + lane) * 8);
      acc0 = __builtin_amdgcn_mfma_f32_16x16x32_bf16(a0, bf, acc0, 0, 0, 0);
      acc1 = __builtin_amdgcn_mfma_f32_16x16x32_bf16(a1, bf, acc1, 0, 0, 0);
    }
    int l = nt * 16 + lr;
    if (l < 40) {
#pragma unroll
      for (int r = 0; r < 4; ++r) {
        int q0 = lh * 4 + r;                       // < 16
        simb[ph][q0][l] = acc0[r] * rQ[ph][q0] * rS[ph][l];
        int q1 = 16 + lh * 4 + r;
        if (q1 < 30) simb[ph][q1][l] = acc1[r] * rQ[ph][q1] * rS[ph][l];
      }
    }
  }
  __syncthreads();

  // duplicate-safe top-5 pooling on 90 threads
  if (tid < 90) {
    const int m = tid / 30, q = tid - m * 30;
    const float* row = (m == 0) ? &simb[0][q][0] : (m == 1) ? &simb[1][q][0] : (ohl + q * 41);
    float thr = 3.4e38f;
    int got = 0;
    float sum = 0.f, maxv = 0.f;
    while (got < 5) {
      float mx = -3.4e38f;
      int c = 0;
      for (int l = 0; l < 40; ++l) {
        float v = row[l];
        if (v < thr) {
          if (v > mx) { mx = v; c = 1; }
          else if (v == mx) { c++; }
        }
      }
      if (c == 0) break;  // safety: never hang
      if (got == 0) maxv = mx;
      int take = (c < 5 - got) ? c : (5 - got);
      sum += mx * (float)take;
      got += take;
      thr = mx;
    }
    feats[q][m * 2 + 0] = maxv;
    feats[q][m * 2 + 1] = sum * 0.2f;
  }
  __syncthreads();
  if (tid < 30) {
    float z = lin_b[0];
#pragma unroll
    for (int i = 0; i < 6; ++i) z += feats[tid][i] * lin_w[i];
    lo[tid] = 1.0f / (1.0f + expf(-z));
  }
  __syncthreads();
  if (tid == 0) {
    float sum = 0.f;
    for (int q = 0; q < 30; ++q) sum += lo[q];
    out[1 + bs] = sum * (1.0f / 30.0f);
  }
}

__global__ __launch_bounds__(256) void k_loss(const int* __restrict__ tsent,
                                              const int* __restrict__ tdoc,
                                              float* __restrict__ out) {
  __shared__ float red[256];
  __shared__ float sent_loss_sh;
  const int tid = threadIdx.x;
  float local = 0.f;
  for (int i = tid; i < 1024; i += 256) {
    float p = out[1 + i];
    float t = (float)tsent[i];
    float lp = fmaxf(logf(p), -100.f);
    float l1 = fmaxf(logf(1.f - p), -100.f);
    local += -(t * lp + (1.f - t) * l1);
  }
  red[tid] = local;
  __syncthreads();
  for (int off = 128; off > 0; off >>= 1) {
    if (tid < off) red[tid] += red[tid + off];
    __syncthreads();
  }
  if (tid == 0) sent_loss_sh = red[0] * (1.0f / 1024.0f);
  __syncthreads();
  float dterm = 0.f;
  if (tid < 32) {
    float mx = out[1 + tid * 32];
    for (int s2 = 1; s2 < 32; ++s2) mx = fmaxf(mx, out[1 + tid * 32 + s2]);
    out[1025 + tid] = mx;
    float t = (float)tdoc[tid];
    float lp = fmaxf(logf(mx), -100.f);
    float l1 = fmaxf(logf(1.f - mx), -100.f);
    dterm = -(t * lp + (1.f - t) * l1);
  }
  red[tid] = dterm;
  __syncthreads();
  for (int off = 128; off > 0; off >>= 1) {
    if (tid < off) red[tid] += red[tid + off];
    __syncthreads();
  }
  if (tid == 0) out[0] = 0.5f * (sent_loss_sh + red[0] * (1.0f / 32.0f));
}

extern "C" void kernel_launch(void* const* d_in, const int* in_sizes, int n_in,
                              void* d_out, int out_size, void* d_ws, size_t ws_size,
                              hipStream_t stream) {
  const int*   question     = (const int*)d_in[0];
  const int*   sentences    = (const int*)d_in[1];
  const int*   target_sents = (const int*)d_in[2];
  const int*   target_docs  = (const int*)d_in[3];
  const float* oneh         = (const float*)d_in[4];
  const float* embeds       = (const float*)d_in[5];
  const float* filters      = (const float*)d_in[6];
  const float* lin_w        = (const float*)d_in[7];
  const float* lin_b        = (const float*)d_in[8];
  float* out = (float*)d_out;

  // workspace layout:
  ushort* fB  = (ushort*)d_ws;             // 480*64*8        = 245,760 ush (491.5 KB)
  ushort* seb = fB  + 245760;              // 1024*10*3*512   = 15,728,640 ush (30 MB)
  ushort* scb = seb + 15728640;            // 1024*8*3*512    = 12,582,912 ush (24 MB)
  ushort* qeb = scb + 12582912;            // 32*10*2*512     = 327,680 ush
  ushort* qcb = qeb + 327680;              // 32*8*2*512      = 262,144 ush
  float*  rs0 = (float*)(qcb + 262144);    // 1024*40
  float*  rs1 = rs0 + 40960;               // 1024*40
  float*  rq0 = rs1 + 40960;               // 32*30
  float*  rq1 = rq0 + 960;                 // 32*30

  k_prepB<<<480, 64, 0, stream>>>(filters, fB);
  k_conv_all<<<1056, 256, 0, stream>>>(question, sentences, embeds, fB,
                                       seb, scb, qeb, qcb, rs0, rs1, rq0, rq1);
  k_sim<<<1024, 256, 0, stream>>>(oneh, qeb, seb, qcb, scb, rq0, rs0, rq1, rs1,
                                  lin_w, lin_b, out);
  k_loss<<<1, 256, 0, stream>>>(target_sents, target_docs, out);
}